// Round 1
// baseline (43.213 us; speedup 1.0000x reference)
//
#include <hip/hip_runtime.h>

// Problem geometry (fixed by the reference):
//   inputs: [32, 8192, 256] f32 ; bins = idx>>7 (64 bins x 128 rows each)
//   out[b, bin, d] = (1/128) * sum_{r<128} in[b, bin*128 + r, d]
constexpr int BATCH        = 32;
constexpr int DIM1         = 8192;
constexpr int DIM2         = 256;
constexpr int NUM_BINS     = 64;
constexpr int ROWS_PER_BIN = DIM1 / NUM_BINS;   // 128
constexpr int DQ           = DIM2 / 4;          // 64 float4 quads per row
constexpr int ROW_GROUPS   = 4;
constexpr int ROWS_PER_RG  = ROWS_PER_BIN / ROW_GROUPS;  // 32

// One block per (b, bin). 256 threads = 64 d-quads x 4 row-groups.
// Each thread sums 32 rows of one float4 quad (fully coalesced: a wave's 64
// lanes read 1 KiB contiguous per iteration), then 4-way LDS reduce + store.
__global__ __launch_bounds__(256) void mean_bin_kernel(const float* __restrict__ in,
                                                       float* __restrict__ out) {
    const int blk = blockIdx.x;          // b*64 + bin
    const int b   = blk >> 6;
    const int bin = blk & 63;
    const int t   = threadIdx.x;
    const int dq  = t & (DQ - 1);        // which float4 quad of dim2
    const int rg  = t >> 6;              // which row-group (0..3)

    const float4* base =
        (const float4*)(in + ((size_t)b * DIM1 + (size_t)bin * ROWS_PER_BIN) * DIM2);
    const float4* p = base + (size_t)(rg * ROWS_PER_RG) * DQ + dq;

    float4 acc = make_float4(0.f, 0.f, 0.f, 0.f);
#pragma unroll 8
    for (int r = 0; r < ROWS_PER_RG; ++r) {
        float4 v = p[(size_t)r * DQ];
        acc.x += v.x; acc.y += v.y; acc.z += v.z; acc.w += v.w;
    }

    __shared__ float4 lds[ROW_GROUPS][DQ];
    lds[rg][dq] = acc;
    __syncthreads();

    if (t < DQ) {
        float4 a0 = lds[0][t];
        float4 a1 = lds[1][t];
        float4 a2 = lds[2][t];
        float4 a3 = lds[3][t];
        // reference: sums / (128.0f + 1e-8f); in fp32, 128.0f + 1e-8f == 128.0f
        const float scale = 1.0f / 128.0f;
        float4 s;
        s.x = (a0.x + a1.x + a2.x + a3.x) * scale;
        s.y = (a0.y + a1.y + a2.y + a3.y) * scale;
        s.z = (a0.z + a1.z + a2.z + a3.z) * scale;
        s.w = (a0.w + a1.w + a2.w + a3.w) * scale;
        float4* o = (float4*)out + ((size_t)b * NUM_BINS + bin) * DQ + t;
        *o = s;
    }
}

extern "C" void kernel_launch(void* const* d_in, const int* in_sizes, int n_in,
                              void* d_out, int out_size, void* d_ws, size_t ws_size,
                              hipStream_t stream) {
    const float* in = (const float*)d_in[0];
    float* out = (float*)d_out;
    const int grid = BATCH * NUM_BINS;   // 2048 blocks
    mean_bin_kernel<<<grid, 256, 0, stream>>>(in, out);
}